// Round 5
// baseline (452.815 us; speedup 1.0000x reference)
//
#include <hip/hip_runtime.h>

// NMS 3x3, replicate pad, strict >, max seeded at 0 (center tap zeroed).
// x: (8, 32, 512, 512) fp32. out = x * (x > max(0, 8 neighbors)).
//
// v4: explicit 2-row software pipeline, loads-before-stores.
// v3 (plain stores) dropped the kernel under the 163 us harness fills, but
// its per-row wait shape was still store->load->wait == effective vmcnt(0).
// Here each row's load is issued one full row-compute before its use and
// always ahead of that iteration's stores, with STATIC buffer names (v2's
// modular ring collapsed to VGPR=40 with loads re-sunk). Steady-state wait
// is vmcnt(4): store-acks and prefetches stay in flight.
//
// One wave owns a full 512-wide row (8 cols/lane as 2x float4), streams a
// 32-row chunk. Vertical window rolls in registers; horizontal neighbors
// in-register + __shfl at lane seams. No LDS, no __syncthreads. Replicate
// pad via clamped row/col: clamped neighbor == center -> strict > fails ->
// border 0, exactly matching the reference.

#define IMG_W 512
#define IMG_H 512
#define NPLANES 256          // 8 * 32
#define CHUNK 32             // rows per wave-task -> 4096 waves, 16/CU
#define THREADS 256          // 4 waves per block
#define WAVES_PER_BLOCK (THREADS / 64)
#define CHUNKS_PER_PLANE (IMG_H / CHUNK)   // 16

typedef float v4f __attribute__((ext_vector_type(4)));

static_assert(IMG_W == 64 * 8, "one wave covers a full row at 8 floats/lane");
static_assert(IMG_H % CHUNK == 0, "chunks divide evenly");
static_assert(CHUNK % 2 == 0, "2-row pipeline");

__device__ __forceinline__ void load_row(const float* __restrict__ base, int r,
                                         float (&d)[8]) {
    const v4f a = *(const v4f*)(base + (size_t)r * IMG_W);
    const v4f b = *(const v4f*)(base + (size_t)r * IMG_W + 4);
    d[0] = a.x; d[1] = a.y; d[2] = a.z; d[3] = a.w;
    d[4] = b.x; d[5] = b.y; d[6] = b.z; d[7] = b.w;
}

// lr[i] = max(left_i, right_i) (center excluded); hm[i] = max(l,c,r).
__device__ __forceinline__ void row_stats(const float (&d)[8], int lane,
                                          float (&lr)[8], float (&hm)[8]) {
    float lnb = __shfl_up(d[7], 1);          // lane-1's col 8l-1
    lnb = (lane == 0) ? d[0] : lnb;          // replicate col 0
    float rnb = __shfl_down(d[0], 1);        // lane+1's col 8l+8
    rnb = (lane == 63) ? d[7] : rnb;         // replicate col 511

    lr[0] = fmaxf(lnb,  d[1]);
    lr[1] = fmaxf(d[0], d[2]);
    lr[2] = fmaxf(d[1], d[3]);
    lr[3] = fmaxf(d[2], d[4]);
    lr[4] = fmaxf(d[3], d[5]);
    lr[5] = fmaxf(d[4], d[6]);
    lr[6] = fmaxf(d[5], d[7]);
    lr[7] = fmaxf(d[6], rnb);
#pragma unroll
    for (int i = 0; i < 8; ++i) hm[i] = fmaxf(lr[i], d[i]);
}

__device__ __forceinline__ void emit_row(float* __restrict__ oimg, int r,
                                         const float (&cen)[8],
                                         const float (&hmA)[8],
                                         const float (&hmB)[8],
                                         const float (&lrC)[8]) {
    float o[8];
#pragma unroll
    for (int i = 0; i < 8; ++i) {
        float m = fmaxf(fmaxf(hmA[i], hmB[i]), lrC[i]);
        m = fmaxf(m, 0.0f);                          // center tap zeroed
        o[i] = (cen[i] > m) ? cen[i] : 0.0f;
    }
    *(v4f*)(oimg + (size_t)r * IMG_W)     = (v4f){ o[0], o[1], o[2], o[3] };
    *(v4f*)(oimg + (size_t)r * IMG_W + 4) = (v4f){ o[4], o[5], o[6], o[7] };
}

__global__ __launch_bounds__(THREADS, 4)
void nms3x3_kernel(const float* __restrict__ x, float* __restrict__ out) {
    const int wid   = blockIdx.x * WAVES_PER_BLOCK + (threadIdx.x >> 6);
    const int lane  = threadIdx.x & 63;
    const int plane = wid / CHUNKS_PER_PLANE;
    const int chunk = wid % CHUNKS_PER_PLANE;
    const int r0    = chunk * CHUNK;

    const float* img  = x   + (size_t)plane * IMG_H * IMG_W + lane * 8;
    float*       oimg = out + (size_t)plane * IMG_H * IMG_W + lane * 8;

    // Rolling state for rows r-1 (pHm), r (cd/cLr/cHm), r+1 (nd, raw).
    float pHm[8];
    float cd[8], cLr[8], cHm[8];
    float nd[8];

    // Prologue: issue 3 loads back-to-back, then stats.
    {
        float td[8], junk[8];
        load_row(img, (r0 > 0) ? r0 - 1 : 0, td);
        load_row(img, r0,     cd);
        load_row(img, r0 + 1, nd);               // r0+1 <= 481 < 512
        row_stats(td, lane, junk, pHm);
        row_stats(cd, lane, cLr, cHm);
    }

#pragma unroll 4
    for (int k = 0; k < CHUNK; k += 2) {
        const int r  = r0 + k;
        const int r2 = (r + 2 < IMG_H) ? r + 2 : IMG_H - 1;
        const int r3 = (r + 3 < IMG_H) ? r + 3 : IMG_H - 1;

        float fd[8], gd[8];
        float nLr[8], nHm[8], fLr[8], fHm[8];

        // --- row r ---
        load_row(img, r2, fd);                   // prefetch r+2 (before stores)
        row_stats(nd, lane, nLr, nHm);           // waits nd only (vmcnt(4))
        emit_row(oimg, r, cd, pHm, nHm, cLr);    // store row r

        // --- row r+1 ---
        load_row(img, r3, gd);                   // prefetch r+3 (before stores)
        row_stats(fd, lane, fLr, fHm);           // waits fd only
        emit_row(oimg, r + 1, nd, cHm, fHm, nLr);

        // --- rotate (static names; renamed away under unroll) ---
#pragma unroll
        for (int i = 0; i < 8; ++i) {
            pHm[i] = nHm[i];
            cd[i]  = fd[i];
            cLr[i] = fLr[i];
            cHm[i] = fHm[i];
            nd[i]  = gd[i];
        }
    }
}

extern "C" void kernel_launch(void* const* d_in, const int* in_sizes, int n_in,
                              void* d_out, int out_size, void* d_ws, size_t ws_size,
                              hipStream_t stream) {
    const float* x = (const float*)d_in[0];
    float* out     = (float*)d_out;
    const int total_waves = NPLANES * CHUNKS_PER_PLANE;        // 4096
    dim3 grid(total_waves / WAVES_PER_BLOCK);                  // 1024 blocks
    nms3x3_kernel<<<grid, dim3(THREADS), 0, stream>>>(x, out);
}

// Round 6
// 443.721 us; speedup vs baseline: 1.0205x; 1.0205x over previous
//
#include <hip/hip_runtime.h>

// NMS 3x3, replicate pad, strict >, max seeded at 0 (center tap zeroed).
// x: (8, 32, 512, 512) fp32. out = x * (x > max(0, 8 neighbors)).
//
// v5: depth-3 register pipeline. Evidence through v4: EVERY variant's write
// stream pins at ~1.6 TB/s (nt or plain), waves spend ~12K cy/row in waits,
// because each row's data-wait allowed only the current iteration's ops
// outstanding -> stores issued ~1 row earlier had to RETIRE before each
// row's compute (store-ack under congestion = thousands of cy). Fix: 5-row
// register ring, prefetch row r+4 at row r (3 iterations ahead), strict
// loads->compute->stores order. Data-waits become vmcnt(12): only stores
// >=4 iterations old must retire. Full unroll makes all %5 indices static
// (no scratch), and register renaming kills the carry copies.
//
// One wave owns a full 512-wide row (8 cols/lane, 2x dwordx4), streams a
// 32-row chunk. Horizontal neighbors in-register + __shfl at lane seams;
// replicate pad via clamped row/col (clamped neighbor == center -> strict >
// fails -> border 0, exactly matching the reference).

#define IMG_W 512
#define IMG_H 512
#define NPLANES 256          // 8 * 32
#define CHUNK 32             // rows per wave-task -> 4096 waves, 16/CU
#define THREADS 256          // 4 waves per block
#define WAVES_PER_BLOCK (THREADS / 64)
#define CHUNKS_PER_PLANE (IMG_H / CHUNK)   // 16

typedef float v4f __attribute__((ext_vector_type(4)));

static_assert(IMG_W == 64 * 8, "one wave covers a full row at 8 floats/lane");
static_assert(IMG_H % CHUNK == 0, "chunks divide evenly");

__device__ __forceinline__ void load_row(const float* __restrict__ base, int r,
                                         float (&d)[8]) {
    const v4f a = *(const v4f*)(base + (size_t)r * IMG_W);
    const v4f b = *(const v4f*)(base + (size_t)r * IMG_W + 4);
    d[0] = a.x; d[1] = a.y; d[2] = a.z; d[3] = a.w;
    d[4] = b.x; d[5] = b.y; d[6] = b.z; d[7] = b.w;
}

// lr[i] = max(left_i, right_i) (center excluded); hm[i] = max(l,c,r).
__device__ __forceinline__ void row_stats(const float (&d)[8], int lane,
                                          float (&lr)[8], float (&hm)[8]) {
    float lnb = __shfl_up(d[7], 1);          // lane-1's col 8l-1
    lnb = (lane == 0) ? d[0] : lnb;          // replicate col 0
    float rnb = __shfl_down(d[0], 1);        // lane+1's col 8l+8
    rnb = (lane == 63) ? d[7] : rnb;         // replicate col 511

    lr[0] = fmaxf(lnb,  d[1]);
    lr[1] = fmaxf(d[0], d[2]);
    lr[2] = fmaxf(d[1], d[3]);
    lr[3] = fmaxf(d[2], d[4]);
    lr[4] = fmaxf(d[3], d[5]);
    lr[5] = fmaxf(d[4], d[6]);
    lr[6] = fmaxf(d[5], d[7]);
    lr[7] = fmaxf(d[6], rnb);
#pragma unroll
    for (int i = 0; i < 8; ++i) hm[i] = fmaxf(lr[i], d[i]);
}

__global__ __launch_bounds__(THREADS, 4)
void nms3x3_kernel(const float* __restrict__ x, float* __restrict__ out) {
    const int wid   = blockIdx.x * WAVES_PER_BLOCK + (threadIdx.x >> 6);
    const int lane  = threadIdx.x & 63;
    const int plane = wid / CHUNKS_PER_PLANE;
    const int chunk = wid % CHUNKS_PER_PLANE;
    const int r0    = chunk * CHUNK;
    const int rmax  = min(r0 + CHUNK + 1, IMG_H - 1);  // last row ever consumed

    const float* img  = x   + (size_t)plane * IMG_H * IMG_W + lane * 8;
    float*       oimg = out + (size_t)plane * IMG_H * IMG_W + lane * 8;

    // 5-slot ring of raw rows. At iteration k (output row r = r0+k):
    //   R[k%5]=row r, R[(k+1)%5]=r+1 (consumed), R[(k+2)%5], R[(k+3)%5] in
    //   flight/held, R[(k+4)%5] <- load row r+4 issued this iteration.
    float R[5][8];
    float pHm[8], cHm[8], cLr[8];   // hm(r-1), hm(r), lr(r)

    // Prologue: 5 row-loads back-to-back, then stats.
    {
        float td[8], junk[8];
        load_row(img, (r0 > 0) ? r0 - 1 : 0, td);
        load_row(img, r0,     R[0]);
        load_row(img, r0 + 1, R[1]);
        load_row(img, r0 + 2, R[2]);
        load_row(img, r0 + 3, R[3]);     // r0+3 <= 483 < 512
        row_stats(td,   lane, junk, pHm);
        row_stats(R[0], lane, cLr,  cHm);
    }

#pragma unroll
    for (int k = 0; k < CHUNK; ++k) {
        const int r = r0 + k;

        // 1. Prefetch row r+4 (3 iterations ahead of its consumption).
        const int rf = (r + 4 <= rmax) ? r + 4 : rmax;   // clamped re-loads hit L1
        load_row(img, rf, R[(k + 4) % 5]);

        // 2. Stats of row r+1 (loaded 3 iterations ago -> wait ~vmcnt(12)).
        float nLr[8], nHm[8];
        row_stats(R[(k + 1) % 5], lane, nLr, nHm);

        // 3. Output row r.
        float o[8];
#pragma unroll
        for (int i = 0; i < 8; ++i) {
            float m = fmaxf(fmaxf(pHm[i], nHm[i]), cLr[i]);
            m = fmaxf(m, 0.0f);                          // center tap zeroed
            const float c = R[k % 5][i];
            o[i] = (c > m) ? c : 0.0f;
        }

        // 4. Stores last.
        *(v4f*)(oimg + (size_t)r * IMG_W)     = (v4f){ o[0], o[1], o[2], o[3] };
        *(v4f*)(oimg + (size_t)r * IMG_W + 4) = (v4f){ o[4], o[5], o[6], o[7] };

        // 5. Carry (renamed away under full unroll).
#pragma unroll
        for (int i = 0; i < 8; ++i) {
            pHm[i] = cHm[i];
            cHm[i] = nHm[i];
            cLr[i] = nLr[i];
        }
    }
}

extern "C" void kernel_launch(void* const* d_in, const int* in_sizes, int n_in,
                              void* d_out, int out_size, void* d_ws, size_t ws_size,
                              hipStream_t stream) {
    const float* x = (const float*)d_in[0];
    float* out     = (float*)d_out;
    const int total_waves = NPLANES * CHUNKS_PER_PLANE;        // 4096
    dim3 grid(total_waves / WAVES_PER_BLOCK);                  // 1024 blocks
    nms3x3_kernel<<<grid, dim3(THREADS), 0, stream>>>(x, out);
}

// Round 7
// 437.910 us; speedup vs baseline: 1.0340x; 1.0133x over previous
//
#include <hip/hip_runtime.h>

// NMS 3x3, replicate pad, strict >, max seeded at 0 (center tap zeroed).
// x: (8, 32, 512, 512) fp32. out = x * (x > max(0, 8 neighbors)).
//
// v6: batch-issue design. v1-v5 all converged to ~165 us (~3.3 TB/s)
// because per-wave load issue was capped at ~1 row per memory latency:
// avg in-flight = 2.5 TB/s x 375 ns = ~450 B/wave. Loop-carried prefetch
// (depth 1 or 3) never fixed the duty cycle. Here each wave owns just 8
// output rows and issues ALL 10 row-loads upfront (20 KB in flight, 10
// distinct NAMED arrays -> no dynamic indexing for the compiler to mangle),
// then computes/stores row by row. Waits allow all newer loads AND all
// stores to stay outstanding (stores issue after all loads -> no wait can
// force store retirement, structurally). 16384 waves (64/CU) keep
// replacement pressure high.
//
// One wave owns a full 512-wide row (8 cols/lane as 2x float4). Horizontal
// neighbors in-register + __shfl at lane seams. Replicate pad via clamped
// row/col: clamped neighbor == center -> strict > fails -> border 0,
// exactly matching the reference.

#define IMG_W 512
#define IMG_H 512
#define NPLANES 256          // 8 * 32
#define CHUNK 8              // output rows per wave -> 64 chunks/plane
#define THREADS 256          // 4 waves per block
#define WAVES_PER_BLOCK (THREADS / 64)
#define CHUNKS_PER_PLANE (IMG_H / CHUNK)   // 64

typedef float v4f __attribute__((ext_vector_type(4)));

static_assert(IMG_W == 64 * 8, "one wave covers a full row at 8 floats/lane");
static_assert(IMG_H % CHUNK == 0, "chunks divide evenly");

__device__ __forceinline__ void load_row(const float* __restrict__ base, int r,
                                         float (&d)[8]) {
    const v4f a = *(const v4f*)(base + (size_t)r * IMG_W);
    const v4f b = *(const v4f*)(base + (size_t)r * IMG_W + 4);
    d[0] = a.x; d[1] = a.y; d[2] = a.z; d[3] = a.w;
    d[4] = b.x; d[5] = b.y; d[6] = b.z; d[7] = b.w;
}

// lr[i] = max(left_i, right_i) (center excluded); hm[i] = max(l,c,r).
__device__ __forceinline__ void row_stats(const float (&d)[8], int lane,
                                          float (&lr)[8], float (&hm)[8]) {
    float lnb = __shfl_up(d[7], 1);          // lane-1's col 8l-1
    lnb = (lane == 0) ? d[0] : lnb;          // replicate col 0
    float rnb = __shfl_down(d[0], 1);        // lane+1's col 8l+8
    rnb = (lane == 63) ? d[7] : rnb;         // replicate col 511

    lr[0] = fmaxf(lnb,  d[1]);
    lr[1] = fmaxf(d[0], d[2]);
    lr[2] = fmaxf(d[1], d[3]);
    lr[3] = fmaxf(d[2], d[4]);
    lr[4] = fmaxf(d[3], d[5]);
    lr[5] = fmaxf(d[4], d[6]);
    lr[6] = fmaxf(d[5], d[7]);
    lr[7] = fmaxf(d[6], rnb);
#pragma unroll
    for (int i = 0; i < 8; ++i) hm[i] = fmaxf(lr[i], d[i]);
}

__global__ __launch_bounds__(THREADS)
void nms3x3_kernel(const float* __restrict__ x, float* __restrict__ out) {
    const int wid   = blockIdx.x * WAVES_PER_BLOCK + (threadIdx.x >> 6);
    const int lane  = threadIdx.x & 63;
    const int plane = wid >> 6;              // / CHUNKS_PER_PLANE
    const int chunk = wid & 63;              // % CHUNKS_PER_PLANE
    const int r0    = chunk * CHUNK;

    const float* img  = x   + (size_t)plane * IMG_H * IMG_W + lane * 8;
    float*       oimg = out + (size_t)plane * IMG_H * IMG_W + lane * 8;

    // ---- Batch-issue all 10 raw-row loads (rows r0-1 .. r0+8, clamped). ----
    float d0[8], d1[8], d2[8], d3[8], d4[8], d5[8], d6[8], d7[8], d8[8], d9[8];
    const int rT = (r0 > 0) ? r0 - 1 : 0;
    const int rB = (r0 + CHUNK < IMG_H) ? r0 + CHUNK : IMG_H - 1;
    load_row(img, rT,     d0);
    load_row(img, r0 + 0, d1);
    load_row(img, r0 + 1, d2);
    load_row(img, r0 + 2, d3);
    load_row(img, r0 + 3, d4);
    load_row(img, r0 + 4, d5);
    load_row(img, r0 + 5, d6);
    load_row(img, r0 + 6, d7);
    load_row(img, r0 + 7, d8);
    load_row(img, rB,     d9);

    // ---- Rolling stats + per-row emit; stores all issue after all loads. ----
    float hmP[8], hmC[8], lrC[8], junk[8];
    row_stats(d0, lane, junk, hmP);          // hm(r0-1)
    row_stats(d1, lane, lrC, hmC);           // lr/hm(r0)

#define ROW_STEP(K, DC, DN)                                                    \
    {                                                                          \
        float lrN[8], hmN[8];                                                  \
        row_stats(DN, lane, lrN, hmN);                                         \
        float o[8];                                                            \
        _Pragma("unroll")                                                      \
        for (int i = 0; i < 8; ++i) {                                          \
            float m = fmaxf(fmaxf(hmP[i], hmN[i]), lrC[i]);                    \
            m = fmaxf(m, 0.0f);                                                \
            o[i] = (DC[i] > m) ? DC[i] : 0.0f;                                 \
        }                                                                      \
        *(v4f*)(oimg + (size_t)(r0 + K) * IMG_W)                               \
            = (v4f){ o[0], o[1], o[2], o[3] };                                 \
        *(v4f*)(oimg + (size_t)(r0 + K) * IMG_W + 4)                           \
            = (v4f){ o[4], o[5], o[6], o[7] };                                 \
        _Pragma("unroll")                                                      \
        for (int i = 0; i < 8; ++i) {                                          \
            hmP[i] = hmC[i];                                                   \
            hmC[i] = hmN[i];                                                   \
            lrC[i] = lrN[i];                                                   \
        }                                                                      \
    }

    ROW_STEP(0, d1, d2)
    ROW_STEP(1, d2, d3)
    ROW_STEP(2, d3, d4)
    ROW_STEP(3, d4, d5)
    ROW_STEP(4, d5, d6)
    ROW_STEP(5, d6, d7)
    ROW_STEP(6, d7, d8)
    ROW_STEP(7, d8, d9)
#undef ROW_STEP
}

extern "C" void kernel_launch(void* const* d_in, const int* in_sizes, int n_in,
                              void* d_out, int out_size, void* d_ws, size_t ws_size,
                              hipStream_t stream) {
    const float* x = (const float*)d_in[0];
    float* out     = (float*)d_out;
    const int total_waves = NPLANES * CHUNKS_PER_PLANE;        // 16384
    dim3 grid(total_waves / WAVES_PER_BLOCK);                  // 4096 blocks
    nms3x3_kernel<<<grid, dim3(THREADS), 0, stream>>>(x, out);
}